// Round 2
// 265.580 us; speedup vs baseline: 1.0027x; 1.0027x over previous
//
#include <hip/hip_runtime.h>

typedef __bf16 bf16;
typedef bf16 bf16x4 __attribute__((ext_vector_type(4)));
typedef bf16 bf16x8 __attribute__((ext_vector_type(8)));
typedef float floatx4 __attribute__((ext_vector_type(4)));
typedef unsigned int u32;

#define B_ 8
#define S_ 2048
#define I_ 1024
#define H_ 64
#define NEG_INF_ -1000000000.0f

// async global->LDS 16B/lane: LDS dst = wave-uniform base + lane*16
__device__ __forceinline__ void async_cp16(bf16* lds_base, const bf16* g_base, int lane) {
    __builtin_amdgcn_global_load_lds(
        (const __attribute__((address_space(1))) u32*)(g_base + lane * 8),
        (__attribute__((address_space(3))) u32*)lds_base, 16, 0, 0);
}

// counted waits + raw barrier (T3/T4): loads stay in flight ACROSS barriers
template<int N> __device__ __forceinline__ void wait_vm() {
    asm volatile("s_waitcnt vmcnt(%0)" :: "n"(N) : "memory");
}
__device__ __forceinline__ void wait_lgkm0() {
    asm volatile("s_waitcnt lgkmcnt(0)" ::: "memory");
}
__device__ __forceinline__ void barrier_() {
    asm volatile("" ::: "memory");
    __builtin_amdgcn_s_barrier();
    asm volatile("" ::: "memory");
}
// pin VMEM issue order: nothing crosses (rule #18/#21 — counted vmcnt needs
// program-order issue; plain loads & global_load_lds don't alias so LLVM may
// otherwise swap them)
__device__ __forceinline__ void fence_order() {
    __builtin_amdgcn_sched_barrier(0);
    asm volatile("" ::: "memory");
}

// ---------------- Kernel A: fold scale + convert + PACK weights ----------------
// Wc2: 8 K-slabs, each [192 rows][136 cols] bf16 (cols 128..135 pad).
__global__ void conv_w(const float* __restrict__ Wq, const float* __restrict__ bq,
                       const float* __restrict__ Wk, const float* __restrict__ bk,
                       const float* __restrict__ Wv, const float* __restrict__ bv,
                       bf16* __restrict__ Wc2, float* __restrict__ bc) {
    int idx = blockIdx.x * 256 + threadIdx.x;   // 0 .. 192*1024-1
    int n = idx >> 10, i = idx & 1023;
    float v;
    if (n < 64)       v = Wq[n * I_ + i] * 0.125f;
    else if (n < 128) v = Wk[(n - 64) * I_ + i];
    else              v = Wv[(n - 128) * I_ + i];
    int s = i >> 7, kl = i & 127;
    Wc2[(size_t)s * 26112 + n * 136 + kl] = (bf16)v;
    if (idx < 192) {
        float bb = (idx < 64) ? bq[idx] * 0.125f
                 : (idx < 128) ? bk[idx - 64] : bv[idx - 128];
        bc[idx] = bb;
    }
}

// ---------------- Kernel B: QKV projection GEMM ----------------
// Grid 512 (M-tile 32), block 256 (4 waves), BK=128 (8 iters).
// X float4 loads prefetched one s-iter ahead; counted vmcnt keeps the prefetch
// in flight across the raw barrier. fence_order pins cps -> X-prefetch issue
// order so wait_vm<4> drains exactly the 13 W cps.
__global__ __launch_bounds__(256, 2) void qkv_gemm(const float* __restrict__ X,
                                                   const bf16* __restrict__ Wc2,
                                                   const float* __restrict__ bc,
                                                   bf16* __restrict__ Qd,
                                                   bf16* __restrict__ Kd2,
                                                   bf16* __restrict__ Vt2) {
    __shared__ __align__(16) bf16 Xs[32 * 136];   // 8704 B
    __shared__ __align__(16) bf16 Ws[26624];      // 53248 B (52 x 512, last 512 pad)

    int tid = threadIdx.x;
    int w = tid >> 6, lane = tid & 63;
    int n = lane & 15, g = lane >> 4;
    int m0 = blockIdx.x * 32;
    int mt = w & 1, nh = (w >> 1) * 96;

    floatx4 zero4 = {0.0f, 0.0f, 0.0f, 0.0f};
    floatx4 acc[6];
#pragma unroll
    for (int t = 0; t < 6; ++t) acc[t] = zero4;

    // X staging map: thread t covers 16 consecutive floats (64 B) of the 32x128 tile
    int xrow = tid >> 3, xcb = (tid & 7) * 16;
    const float* xsrc = X + (size_t)(m0 + xrow) * I_ + xcb;
    bf16* xdst = Xs + xrow * 136 + xcb;

    // prologue: issue X(0)
    float4 xa = *(const float4*)(xsrc);
    float4 xb = *(const float4*)(xsrc + 4);
    float4 xc = *(const float4*)(xsrc + 8);
    float4 xd = *(const float4*)(xsrc + 12);

    for (int s = 0; s < 8; ++s) {
        // ---- stage W slab via async: 52 insts uniform, 13 per wave ----
#pragma unroll
        for (int i = 0; i < 13; ++i) {
            int inst = i * 4 + w;
            async_cp16(Ws + inst * 512, Wc2 + (size_t)s * 26112 + inst * 512, lane);
        }
        // ---- convert prefetched X(s) -> LDS ----
        bf16x8 b0, b1;
        b0[0] = (bf16)xa.x; b0[1] = (bf16)xa.y; b0[2] = (bf16)xa.z; b0[3] = (bf16)xa.w;
        b0[4] = (bf16)xb.x; b0[5] = (bf16)xb.y; b0[6] = (bf16)xb.z; b0[7] = (bf16)xb.w;
        b1[0] = (bf16)xc.x; b1[1] = (bf16)xc.y; b1[2] = (bf16)xc.z; b1[3] = (bf16)xc.w;
        b1[4] = (bf16)xd.x; b1[5] = (bf16)xd.y; b1[6] = (bf16)xd.z; b1[7] = (bf16)xd.w;
        *(bf16x8*)xdst = b0;
        *(bf16x8*)(xdst + 8) = b1;
        // ---- pin order, then prefetch X(s+1); wait leaves only X in flight ----
        fence_order();
        if (s < 7) {
            const float* xp = xsrc + (s + 1) * 128;
            xa = *(const float4*)(xp);
            xb = *(const float4*)(xp + 4);
            xc = *(const float4*)(xp + 8);
            xd = *(const float4*)(xp + 12);
            wait_vm<4>();
        } else {
            wait_vm<0>();
        }
        wait_lgkm0();
        barrier_();

        // ---- compute: 4 k-steps of 32 ----
#pragma unroll
        for (int ks = 0; ks < 4; ++ks) {
            bf16x8 xv = *(bf16x8*)(Xs + (mt * 16 + n) * 136 + ks * 32 + g * 8);
#pragma unroll
            for (int nt = 0; nt < 6; ++nt) {
                bf16x8 wb = *(bf16x8*)(Ws + (nh + nt * 16 + n) * 136 + ks * 32 + g * 8);
                acc[nt] = __builtin_amdgcn_mfma_f32_16x16x32_bf16(xv, wb, acc[nt], 0, 0, 0);
            }
        }
        wait_lgkm0();
        barrier_();
    }

    // ---- epilogue: C/D layout col=lane&15, row=g*4+r ----
    int b = m0 >> 11;
    int sb = (m0 & 2047) + mt * 16 + g * 4;
#pragma unroll
    for (int nt = 0; nt < 6; ++nt) {
        int ng = nh + nt * 16 + n;
        float bias = bc[ng];
        if (ng < 64) {
#pragma unroll
            for (int r = 0; r < 4; ++r)
                Qd[(size_t)(b * S_ + sb + r) * H_ + ng] = (bf16)(acc[nt][r] + bias);
        } else if (ng < 128) {
            int hc = (ng - 64) >> 3, j = (ng - 64) & 7;
#pragma unroll
            for (int r = 0; r < 4; ++r)
                Kd2[((size_t)(b * 8 + hc) * S_ + sb + r) * 8 + j] = (bf16)(acc[nt][r] + bias);
        } else {
            int hh = ng - 128, kc = sb >> 3, jj = sb & 7;
            bf16x4 pk;
#pragma unroll
            for (int r = 0; r < 4; ++r) pk[r] = (bf16)(acc[nt][r] + bias);
            *(bf16x4*)(Vt2 + ((size_t)(b * 256 + kc) * 64 + hh) * 8 + jj) = pk;
        }
    }
}

// ---------------- Kernel C: flash attention, fully pipelined ----------------
// Grid 256 (= 1 block/CU): bid = (b*16+qt)*2 + ksp. Block 512 (8 waves),
// q-tile 128, k-tile 128, 8 kt iters. K/V double-buffered (staged 1 iter
// ahead); masks prefetched 1 iter ahead in registers. ONE barrier per iter;
// Ps is wave-private (wave w writes & reads rows [w*16, w*16+16)) so the
// P-visibility barrier is just a per-wave lgkmcnt(0). No vmcnt(0) drain in
// the main loop.
__global__ __launch_bounds__(512, 2) void attn(const bf16* __restrict__ Qd,
                                               const bf16* __restrict__ Kd2,
                                               const bf16* __restrict__ Vt2,
                                               const int* __restrict__ mask,
                                               float* __restrict__ po,
                                               float* __restrict__ pml) {
    __shared__ __align__(16) bf16 Ks[2][8 * 1040];   // 33280 B
    __shared__ __align__(16) bf16 Vs[2][16 * 528];   // 33792 B
    __shared__ __align__(16) bf16 Ps[128 * 136];     // 34816 B

    int tid = threadIdx.x;
    int w = tid >> 6, lane = tid & 63;
    int n = lane & 15, g = lane >> 4;
    int bid = blockIdx.x;
    int ksp = bid & 1;
    int qt = (bid >> 1) & 15;
    int b = bid >> 5;
    int q0 = qt * 128;

    const bf16* qptr = Qd + (size_t)(b * S_ + q0 + w * 16 + n) * H_ + g * 8;
    bf16x8 qa0 = *(const bf16x8*)qptr;
    bf16x8 qa1 = *(const bf16x8*)(qptr + 32);

    floatx4 zero4 = {0.0f, 0.0f, 0.0f, 0.0f};
    floatx4 o[4];
#pragma unroll
    for (int t = 0; t < 4; ++t) o[t] = zero4;
    float m_i[4], l_i[4];
#pragma unroll
    for (int r = 0; r < 4; ++r) { m_i[r] = -INFINITY; l_i[r] = 0.0f; }

    int kt0 = ksp * 8;
    const int* mbase = mask + (size_t)(b * S_ + q0 + w * 16 + g * 4) * S_ + n;
    int mreg[4][8];

    // ---- prologue: stage KV(kt0) [4 cps], FENCE, then masks(kt0) [32 loads] ----
    {
        async_cp16(&Ks[0][w * 1040],       Kd2 + ((size_t)(b * 8 + w) * S_ + kt0 * 128) * 8, lane);
        async_cp16(&Ks[0][w * 1040 + 512], Kd2 + ((size_t)(b * 8 + w) * S_ + kt0 * 128 + 64) * 8, lane);
        async_cp16(&Vs[0][(w * 2) * 528],     Vt2 + ((size_t)(b * 256 + kt0 * 16 + w * 2) * 64) * 8, lane);
        async_cp16(&Vs[0][(w * 2 + 1) * 528], Vt2 + ((size_t)(b * 256 + kt0 * 16 + w * 2 + 1) * 64) * 8, lane);
        fence_order();   // cps MUST precede mask loads in issue order (vmcnt count)
        const int* mb = mbase + (size_t)kt0 * S_ * 0 + (size_t)kt0 * 128;
#pragma unroll
        for (int r = 0; r < 4; ++r)
#pragma unroll
            for (int nt = 0; nt < 8; ++nt)
                mreg[r][nt] = mb[(size_t)r * S_ + nt * 16];
    }

#pragma unroll 2
    for (int it = 0; it < 8; ++it) {
        int kt = kt0 + it;
        int cur = it & 1;
        bf16* ksc = &Ks[cur][0];
        bf16* vsc = &Vs[cur][0];

        // b1: own KV(kt) done (32 masks stay in flight); prior LDS reads retired
        wait_vm<32>();
        wait_lgkm0();
        barrier_();

        // stage KV(kt+1) into the other buffer (prev-iter readers are past b1)
        if (it < 7) {
            int nxt = cur ^ 1;
            async_cp16(&Ks[nxt][w * 1040],       Kd2 + ((size_t)(b * 8 + w) * S_ + (kt + 1) * 128) * 8, lane);
            async_cp16(&Ks[nxt][w * 1040 + 512], Kd2 + ((size_t)(b * 8 + w) * S_ + (kt + 1) * 128 + 64) * 8, lane);
            async_cp16(&Vs[nxt][(w * 2) * 528],     Vt2 + ((size_t)(b * 256 + (kt + 1) * 16 + w * 2) * 64) * 8, lane);
            async_cp16(&Vs[nxt][(w * 2 + 1) * 528], Vt2 + ((size_t)(b * 256 + (kt + 1) * 16 + w * 2 + 1) * 64) * 8, lane);
        }

        // ---- S = Q K^T ----
        floatx4 s[8];
#pragma unroll
        for (int nt = 0; nt < 8; ++nt) {
            floatx4 a = zero4;
            a = __builtin_amdgcn_mfma_f32_16x16x32_bf16(
                    qa0, *(const bf16x8*)(ksc + g * 1040 + (nt * 16 + n) * 8), a, 0, 0, 0);
            a = __builtin_amdgcn_mfma_f32_16x16x32_bf16(
                    qa1, *(const bf16x8*)(ksc + (4 + g) * 1040 + (nt * 16 + n) * 8), a, 0, 0, 0);
            s[nt] = a;
        }

        // wait masks(kt) only (next KV stays in flight), apply
        if (it < 7) wait_vm<4>(); else wait_vm<0>();
#pragma unroll
        for (int r = 0; r < 4; ++r)
#pragma unroll
            for (int nt = 0; nt < 8; ++nt)
                if (mreg[r][nt] == 0) s[nt][r] = NEG_INF_;

        // prefetch masks(kt+1) — loads sit after the wait asm, so issue order
        // (cps -> mask loads) is pinned by the memory clobber
        if (it < 7) {
            const int* mb = mbase + (size_t)(kt + 1) * 128;
#pragma unroll
            for (int r = 0; r < 4; ++r)
#pragma unroll
                for (int nt = 0; nt < 8; ++nt)
                    mreg[r][nt] = mb[(size_t)r * S_ + nt * 16];
        }

        // ---- online softmax (4 rows' shuffle trees interleaved) ----
        float tm[4];
#pragma unroll
        for (int r = 0; r < 4; ++r) {
            float t = s[0][r];
#pragma unroll
            for (int nt = 1; nt < 8; ++nt) t = fmaxf(t, s[nt][r]);
            tm[r] = t;
        }
#pragma unroll
        for (int off = 1; off < 16; off <<= 1)
#pragma unroll
            for (int r = 0; r < 4; ++r) tm[r] = fmaxf(tm[r], __shfl_xor(tm[r], off, 64));
        float alpha[4], rs[4];
#pragma unroll
        for (int r = 0; r < 4; ++r) {
            float mn = fmaxf(m_i[r], tm[r]);
            alpha[r] = __expf(m_i[r] - mn);
            m_i[r] = mn;
            rs[r] = 0.0f;
        }
#pragma unroll
        for (int r = 0; r < 4; ++r)
#pragma unroll
            for (int nt = 0; nt < 8; ++nt) {
                float p = __expf(s[nt][r] - m_i[r]);
                s[nt][r] = p;
                rs[r] += p;
            }
#pragma unroll
        for (int off = 1; off < 16; off <<= 1)
#pragma unroll
            for (int r = 0; r < 4; ++r) rs[r] += __shfl_xor(rs[r], off, 64);
#pragma unroll
        for (int r = 0; r < 4; ++r) {
            l_i[r] = l_i[r] * alpha[r] + rs[r];
#pragma unroll
            for (int ht = 0; ht < 4; ++ht) o[ht][r] *= alpha[r];
        }

        // ---- P -> LDS (wave-private rows; no barrier needed, just lgkm drain) ----
#pragma unroll
        for (int r = 0; r < 4; ++r)
#pragma unroll
            for (int nt = 0; nt < 8; ++nt)
                Ps[(w * 16 + g * 4 + r) * 136 + nt * 16 + n] = (bf16)s[nt][r];
        wait_lgkm0();

        // ---- O += P V ----
#pragma unroll
        for (int k0 = 0; k0 < 4; ++k0) {
            bf16x8 pa = *(bf16x8*)(Ps + (w * 16 + n) * 136 + k0 * 32 + g * 8);
#pragma unroll
            for (int ht = 0; ht < 4; ++ht) {
                bf16x8 vb = *(bf16x8*)(vsc + (k0 * 4 + g) * 528 + (ht * 16 + n) * 8);
                o[ht] = __builtin_amdgcn_mfma_f32_16x16x32_bf16(pa, vb, o[ht], 0, 0, 0);
            }
        }
    }

    float* pb = po + (size_t)bid * 8192;
#pragma unroll
    for (int ht = 0; ht < 4; ++ht)
#pragma unroll
        for (int r = 0; r < 4; ++r)
            pb[(w * 16 + g * 4 + r) * 64 + ht * 16 + n] = o[ht][r];
    if (n == 0) {
#pragma unroll
        for (int r = 0; r < 4; ++r) {
            pml[(size_t)bid * 256 + w * 16 + g * 4 + r] = m_i[r];
            pml[(size_t)bid * 256 + 128 + w * 16 + g * 4 + r] = l_i[r];
        }
    }
}

// ---------------- Kernel D: merge 2 k-split partials ----------------
__global__ __launch_bounds__(256) void reduce_o(const float* __restrict__ po,
                                                const float* __restrict__ pml,
                                                float* __restrict__ out) {
    int idx = blockIdx.x * 256 + threadIdx.x;   // (q,h): 16384*64
    int h = idx & 63, q = idx >> 6;
    int b = q >> 11, qq = q & 2047;
    int qt = qq >> 7, ql = qq & 127;
    int bid0 = (b * 16 + qt) * 2;
    float m0 = pml[(size_t)bid0 * 256 + ql];
    float l0 = pml[(size_t)bid0 * 256 + 128 + ql];
    float m1 = pml[(size_t)(bid0 + 1) * 256 + ql];
    float l1 = pml[(size_t)(bid0 + 1) * 256 + 128 + ql];
    float M = fmaxf(m0, m1);
    float s0 = __expf(m0 - M), s1 = __expf(m1 - M);
    float den = l0 * s0 + l1 * s1;
    float num = po[(size_t)bid0 * 8192 + ql * 64 + h] * s0
              + po[(size_t)(bid0 + 1) * 8192 + ql * 64 + h] * s1;
    out[(size_t)q * 64 + h] = num / den;
}

extern "C" void kernel_launch(void* const* d_in, const int* in_sizes, int n_in,
                              void* d_out, int out_size, void* d_ws, size_t ws_size,
                              hipStream_t stream) {
    const float* X    = (const float*)d_in[0];
    const int*   mask = (const int*)d_in[1];
    const float* Wq   = (const float*)d_in[2];
    const float* bq   = (const float*)d_in[3];
    const float* Wk   = (const float*)d_in[4];
    const float* bk   = (const float*)d_in[5];
    const float* Wv   = (const float*)d_in[6];
    const float* bv   = (const float*)d_in[7];
    float* out = (float*)d_out;

    char* p = (char*)d_ws;
    bf16* Qd   = (bf16*)p;  p += (size_t)B_ * S_ * H_ * 2;      // 2 MB
    bf16* Kd2  = (bf16*)p;  p += (size_t)B_ * S_ * H_ * 2;      // 2 MB
    bf16* Vt2  = (bf16*)p;  p += (size_t)B_ * S_ * H_ * 2;      // 2 MB
    bf16* Wc2  = (bf16*)p;  p += (size_t)8 * 26112 * 2;         // 417 KB packed W
    float* bc  = (float*)p; p += 1024;
    float* po  = (float*)p; p += (size_t)512 * 8192 * 4;        // 16 MB
    float* pml = (float*)p; p += (size_t)512 * 256 * 4;         // 512 KB

    conv_w<<<dim3(768), dim3(256), 0, stream>>>(Wq, bq, Wk, bk, Wv, bv, Wc2, bc);
    qkv_gemm<<<dim3(512), dim3(256), 0, stream>>>(X, Wc2, bc, Qd, Kd2, Vt2);
    attn<<<dim3(256), dim3(512), 0, stream>>>(Qd, Kd2, Vt2, mask, po, pml);
    reduce_o<<<dim3(4096), dim3(256), 0, stream>>>(po, pml, out);
}